// Round 1
// baseline (1803.365 us; speedup 1.0000x reference)
//
#include <hip/hip_runtime.h>

// B=64, C=256, L=4096. Tokens b-major: t = b*4096 + l.
// ws layout: Xt bf16[262144][256] @0 (128MB); TV bf16[262144][512] @128MB (256MB)
//            (cols 0..255 = T, later overwritten in-place by virt; 256..511 = V)
//            Wtv bf16[512][256] @384MB; Wout2 bf16[256][512]; stats fp32[256]

typedef __attribute__((ext_vector_type(8))) short          v8s;   // 8 x bf16 bits
typedef __attribute__((ext_vector_type(8))) unsigned short v8u;
typedef __attribute__((ext_vector_type(4))) float          f32x4;

#define MFMA16(a, b, c) __builtin_amdgcn_mfma_f32_16x16x32_bf16((a), (b), (c), 0, 0, 0)

static __device__ __forceinline__ unsigned short f2bf(float f) {
  union { float f; unsigned u; } v; v.f = f;
  unsigned r = (v.u + 0x7FFFu + ((v.u >> 16) & 1u)) >> 16;  // RNE
  return (unsigned short)r;
}
static __device__ __forceinline__ float bf2f(unsigned short h) {
  union { unsigned u; float f; } v; v.u = ((unsigned)h) << 16; return v.f;
}

// ---------------- prep: M = Wq^T Wk / 16, W2 = Wout*Wc, bf16 packs, zero stats
__global__ void k_prep(const float* __restrict__ Wq, const float* __restrict__ Wk,
                       const float* __restrict__ Wv, const float* __restrict__ Wc,
                       const float* __restrict__ Wout,
                       unsigned short* __restrict__ Wtv,    // [512][256]
                       unsigned short* __restrict__ Wout2,  // [256][512]
                       float* __restrict__ stats) {
  int bid = blockIdx.x, j = threadIdx.x;
  if (bid < 256) {
    int i = bid;
    float acc = 0.f;
    for (int c = 0; c < 256; ++c) acc += Wq[c * 256 + i] * Wk[c * 256 + j];
    Wtv[i * 256 + j] = f2bf(acc * 0.0625f);               // M row i
    Wtv[(256 + i) * 256 + j] = f2bf(Wv[i * 256 + j]);     // Wv row i
  } else if (bid < 512) {
    int o = bid - 256;
    float acc = 0.f;
    for (int c = 0; c < 256; ++c) acc += Wout[o * 256 + c] * Wc[c * 256 + j];
    Wout2[o * 512 + 256 + j] = f2bf(acc);                 // W2 = Wout*Wc
    Wout2[o * 512 + j] = f2bf(Wout[o * 256 + j]);         // Wout
  } else {
    stats[j] = 0.f;                                        // GN accumulators
  }
}

// ---------------- x (B,C,L) fp32 -> Xt[t][c] bf16 (LDS-tiled 64x64 transpose)
__global__ void k_transpose(const float* __restrict__ x, unsigned short* __restrict__ Xt) {
  __shared__ float tile[64 * 65];
  int bid = blockIdx.x;
  int b = bid >> 8, cb = (bid >> 6) & 3, lb = bid & 63;
  int c0 = cb * 64, l0 = lb * 64, t = threadIdx.x;
#pragma unroll
  for (int i = 0; i < 4; ++i) {
    int idx = i * 256 + t, r = idx >> 4, ch = idx & 15;   // r = c-row, ch = float4 over l
    float4 v = *(const float4*)(x + ((size_t)(b * 256 + c0 + r)) * 4096 + l0 + ch * 4);
    tile[r * 65 + ch * 4 + 0] = v.x; tile[r * 65 + ch * 4 + 1] = v.y;
    tile[r * 65 + ch * 4 + 2] = v.z; tile[r * 65 + ch * 4 + 3] = v.w;
  }
  __syncthreads();
#pragma unroll
  for (int i = 0; i < 2; ++i) {
    int idx = i * 256 + t, r = idx >> 3, ch = idx & 7;    // r = l-row, ch = 8-elem chunk over c
    v8u o;
#pragma unroll
    for (int j = 0; j < 8; ++j) o[j] = f2bf(tile[(ch * 8 + j) * 65 + r]);
    *(v8u*)(Xt + ((size_t)(b * 4096 + l0 + r)) * 256 + c0 + ch * 8) = o;
  }
}

// ---------------- TV = Xt * [M | Wv]^T : M=262144, N=512, K=256. BM=64, BN=512, BK=32
__global__ void k_gemm_tv(const unsigned short* __restrict__ Xt,
                          const unsigned short* __restrict__ Wtv,
                          unsigned short* __restrict__ TV) {
  __shared__ unsigned short As[64 * 40];   // stride 40 elems (80B, 16B-aligned, bank-step 20)
  __shared__ unsigned short Bs[512 * 40];
  int t = threadIdx.x, lane = t & 63, wv = t >> 6;
  size_t t0 = (size_t)blockIdx.x * 64;
  int n0 = wv * 128;
  f32x4 acc[4][8];
#pragma unroll
  for (int mi = 0; mi < 4; ++mi)
#pragma unroll
    for (int ni = 0; ni < 8; ++ni) acc[mi][ni] = (f32x4){0.f, 0.f, 0.f, 0.f};
  int fr = lane & 15, kq = (lane >> 4) * 8;
  for (int kc = 0; kc < 8; ++kc) {
    __syncthreads();
    { int r = t >> 2, ch = t & 3;
      *(v8u*)(As + r * 40 + ch * 8) = *(const v8u*)(Xt + (t0 + r) * 256 + kc * 32 + ch * 8); }
#pragma unroll
    for (int i = 0; i < 8; ++i) {
      int idx = i * 256 + t, r = idx >> 2, ch = idx & 3;
      *(v8u*)(Bs + r * 40 + ch * 8) = *(const v8u*)(Wtv + r * 256 + kc * 32 + ch * 8);
    }
    __syncthreads();
    v8s a[4], b[8];
#pragma unroll
    for (int mi = 0; mi < 4; ++mi) a[mi] = *(const v8s*)(As + (mi * 16 + fr) * 40 + kq);
#pragma unroll
    for (int ni = 0; ni < 8; ++ni) b[ni] = *(const v8s*)(Bs + (n0 + ni * 16 + fr) * 40 + kq);
#pragma unroll
    for (int mi = 0; mi < 4; ++mi)
#pragma unroll
      for (int ni = 0; ni < 8; ++ni) acc[mi][ni] = MFMA16(a[mi], b[ni], acc[mi][ni]);
  }
  int qr = (lane >> 4) * 4;
#pragma unroll
  for (int mi = 0; mi < 4; ++mi)
#pragma unroll
    for (int ni = 0; ni < 8; ++ni)
#pragma unroll
      for (int i = 0; i < 4; ++i)
        TV[(t0 + mi * 16 + qr + i) * 512 + n0 + ni * 16 + (lane & 15)] = f2bf(acc[mi][ni][i]);
}

// ---------------- per-l attention: S = X*T^T (64x64,K=256), softmax rows, virt = P*V
__global__ void k_attn(const unsigned short* __restrict__ Xt,
                       unsigned short* __restrict__ TV) {
  __shared__ unsigned short Xl[64 * 264];  // row-major (b, c), 16B-aligned stride
  __shared__ unsigned short Tl[64 * 264];
  __shared__ float S[64 * 65];             // scores, bank-step 65%32=1 -> conflict-free rows
  __shared__ unsigned short P[64 * 66];    // probs bf16
  __shared__ unsigned short VT[256 * 66];  // V^T (c, d), bank-step 33 -> conflict-free
  int l = blockIdx.x, t = threadIdx.x, lane = t & 63, wv = t >> 6;
#pragma unroll
  for (int i = 0; i < 8; ++i) {
    int idx = i * 256 + t, r = idx >> 5, ch = idx & 31;
    *(v8u*)(Xl + r * 264 + ch * 8) = *(const v8u*)(Xt + ((size_t)(r * 4096 + l)) * 256 + ch * 8);
    *(v8u*)(Tl + r * 264 + ch * 8) = *(const v8u*)(TV + ((size_t)(r * 4096 + l)) * 512 + ch * 8);
  }
#pragma unroll
  for (int i = 0; i < 8; ++i) {           // V rows -> VT columns (coalesced global reads)
    int d = (t >> 5) + i * 8, c0 = (t & 31) * 8;
    v8u v = *(const v8u*)(TV + ((size_t)(d * 4096 + l)) * 512 + 256 + c0);
#pragma unroll
    for (int j = 0; j < 8; ++j) VT[(c0 + j) * 66 + d] = v[j];
  }
  __syncthreads();
  {  // S = Xl * Tl^T
    f32x4 accA[4];
#pragma unroll
    for (int ni = 0; ni < 4; ++ni) accA[ni] = (f32x4){0.f, 0.f, 0.f, 0.f};
    int mr = wv * 16 + (lane & 15), kq = (lane >> 4) * 8;
#pragma unroll
    for (int kc = 0; kc < 8; ++kc) {
      v8s a = *(const v8s*)(Xl + mr * 264 + kc * 32 + kq);
#pragma unroll
      for (int ni = 0; ni < 4; ++ni) {
        v8s b = *(const v8s*)(Tl + (ni * 16 + (lane & 15)) * 264 + kc * 32 + kq);
        accA[ni] = MFMA16(a, b, accA[ni]);
      }
    }
    int qr = (lane >> 4) * 4;
#pragma unroll
    for (int ni = 0; ni < 4; ++ni)
#pragma unroll
      for (int i = 0; i < 4; ++i)
        S[(wv * 16 + qr + i) * 65 + ni * 16 + (lane & 15)] = accA[ni][i];
  }
  __syncthreads();
  if (t < 64) {  // softmax over d (row direction)
    float mx = -1e30f;
    for (int j = 0; j < 64; ++j) mx = fmaxf(mx, S[t * 65 + j]);
    float sum = 0.f;
    for (int j = 0; j < 64; ++j) { float e = __expf(S[t * 65 + j] - mx); S[t * 65 + j] = e; sum += e; }
    float inv = 1.f / sum;
    for (int j = 0; j < 64; ++j) P[t * 66 + j] = f2bf(S[t * 65 + j] * inv);
  }
  __syncthreads();
  {  // virt = P * V  (64x256, K=64) -> overwrite T half of TV (block-local rows)
    f32x4 acc[4][4];
#pragma unroll
    for (int mi = 0; mi < 4; ++mi)
#pragma unroll
      for (int ni = 0; ni < 4; ++ni) acc[mi][ni] = (f32x4){0.f, 0.f, 0.f, 0.f};
    int n0 = wv * 64, kq = (lane >> 4) * 8;
#pragma unroll
    for (int kc = 0; kc < 2; ++kc) {
      v8s a[4], b[4];
#pragma unroll
      for (int mi = 0; mi < 4; ++mi) {
        int base = (mi * 16 + (lane & 15)) * 66 + kc * 32 + kq;
#pragma unroll
        for (int j = 0; j < 8; ++j) a[mi][j] = (short)P[base + j];
      }
#pragma unroll
      for (int ni = 0; ni < 4; ++ni) {
        int base = (n0 + ni * 16 + (lane & 15)) * 66 + kc * 32 + kq;
#pragma unroll
        for (int j = 0; j < 8; ++j) b[ni][j] = (short)VT[base + j];
      }
#pragma unroll
      for (int mi = 0; mi < 4; ++mi)
#pragma unroll
        for (int ni = 0; ni < 4; ++ni) acc[mi][ni] = MFMA16(a[mi], b[ni], acc[mi][ni]);
    }
    int qr = (lane >> 4) * 4;
#pragma unroll
    for (int mi = 0; mi < 4; ++mi)
#pragma unroll
      for (int ni = 0; ni < 4; ++ni)
#pragma unroll
        for (int i = 0; i < 4; ++i)
          TV[((size_t)((mi * 16 + qr + i) * 4096 + l)) * 512 + n0 + ni * 16 + (lane & 15)] =
              f2bf(acc[mi][ni][i]);
  }
}

// ---------------- GN partial sums over virt (per-b), 64 tokens per block
__global__ void k_stats(const unsigned short* __restrict__ TV, float* __restrict__ stats) {
  size_t t0 = (size_t)blockIdx.x * 64;
  int b = (int)(t0 >> 12), t = threadIdx.x;
  float s = 0.f, s2 = 0.f;
#pragma unroll
  for (int i = 0; i < 8; ++i) {
    int idx = i * 256 + t, r = idx >> 5, ch = idx & 31;
    v8u v = *(const v8u*)(TV + (t0 + r) * 512 + ch * 8);
#pragma unroll
    for (int j = 0; j < 8; ++j) { float f = bf2f(v[j]); s += f; s2 += f * f; }
  }
#pragma unroll
  for (int o = 32; o > 0; o >>= 1) { s += __shfl_down(s, o); s2 += __shfl_down(s2, o); }
  __shared__ float wsum[8];
  if ((t & 63) == 0) { wsum[(t >> 6) * 2] = s; wsum[(t >> 6) * 2 + 1] = s2; }
  __syncthreads();
  if (t == 0) {
    atomicAdd(&stats[b], wsum[0] + wsum[2] + wsum[4] + wsum[6]);
    atomicAdd(&stats[64 + b], wsum[1] + wsum[3] + wsum[5] + wsum[7]);
  }
}

__global__ void k_finalize(float* __restrict__ stats) {
  int t = threadIdx.x;
  if (t < 64) {
    const float inv = 1.f / 1048576.f;  // C*L
    float m = stats[t] * inv;
    float var = stats[64 + t] * inv - m * m;
    stats[128 + t] = m;
    stats[192 + t] = rsqrtf(var + 1e-5f);
  }
}

// ---------------- out = [Xt | relu(gn(virt))] * [Wout | W2]^T : K=512, BM=64, BN=256, BK=64
__global__ void k_gemm_out(const unsigned short* __restrict__ Xt,
                           const unsigned short* __restrict__ TV,
                           const unsigned short* __restrict__ Wout2,
                           const float* __restrict__ stats,
                           const float* __restrict__ gamma,
                           const float* __restrict__ beta,
                           float* __restrict__ out) {
  __shared__ unsigned short As[64 * 72];
  __shared__ unsigned short Bs[256 * 72];
  int t = threadIdx.x, lane = t & 63, wv = t >> 6;
  size_t t0 = (size_t)blockIdx.x * 64;
  int b = (int)(t0 >> 12);
  float mean = stats[128 + b], rstd = stats[192 + b];  // uniform per block (64 | 4096)
  int n0 = wv * 64;
  f32x4 acc[4][4];
#pragma unroll
  for (int mi = 0; mi < 4; ++mi)
#pragma unroll
    for (int ni = 0; ni < 4; ++ni) acc[mi][ni] = (f32x4){0.f, 0.f, 0.f, 0.f};
  for (int kc = 0; kc < 8; ++kc) {
    __syncthreads();
#pragma unroll
    for (int i = 0; i < 2; ++i) {  // stage A (64 x 64)
      int idx = i * 256 + t, r = idx >> 3, ch = idx & 7;
      if (kc < 4) {
        *(v8u*)(As + r * 72 + ch * 8) = *(const v8u*)(Xt + (t0 + r) * 256 + kc * 64 + ch * 8);
      } else {
        v8u v = *(const v8u*)(TV + (t0 + r) * 512 + (kc - 4) * 64 + ch * 8);
        int cb = (kc - 4) * 64 + ch * 8;
        float4 g0 = *(const float4*)(gamma + cb), g1 = *(const float4*)(gamma + cb + 4);
        float4 bb0 = *(const float4*)(beta + cb), bb1 = *(const float4*)(beta + cb + 4);
        float gs[8] = {g0.x, g0.y, g0.z, g0.w, g1.x, g1.y, g1.z, g1.w};
        float bs[8] = {bb0.x, bb0.y, bb0.z, bb0.w, bb1.x, bb1.y, bb1.z, bb1.w};
        v8u o;
#pragma unroll
        for (int j = 0; j < 8; ++j) {
          float z = (bf2f(v[j]) - mean) * rstd * gs[j] + bs[j];
          o[j] = f2bf(fmaxf(z, 0.f));
        }
        *(v8u*)(As + r * 72 + ch * 8) = o;
      }
    }
#pragma unroll
    for (int i = 0; i < 8; ++i) {  // stage B (256 x 64)
      int idx = i * 256 + t, r = idx >> 3, ch = idx & 7;
      *(v8u*)(Bs + r * 72 + ch * 8) = *(const v8u*)(Wout2 + r * 512 + kc * 64 + ch * 8);
    }
    __syncthreads();
#pragma unroll
    for (int ks = 0; ks < 2; ++ks) {
      int kq = ks * 32 + (lane >> 4) * 8;
      v8s a[4], bb[4];
#pragma unroll
      for (int mi = 0; mi < 4; ++mi) a[mi] = *(const v8s*)(As + (mi * 16 + (lane & 15)) * 72 + kq);
#pragma unroll
      for (int ni = 0; ni < 4; ++ni)
        bb[ni] = *(const v8s*)(Bs + (n0 + ni * 16 + (lane & 15)) * 72 + kq);
#pragma unroll
      for (int mi = 0; mi < 4; ++mi)
#pragma unroll
        for (int ni = 0; ni < 4; ++ni) acc[mi][ni] = MFMA16(a[mi], bb[ni], acc[mi][ni]);
    }
  }
  int qr = (lane >> 4) * 4, lbase = (int)(t0 & 4095);
#pragma unroll
  for (int mi = 0; mi < 4; ++mi)
#pragma unroll
    for (int ni = 0; ni < 4; ++ni)
#pragma unroll
      for (int i = 0; i < 4; ++i) {
        int ll = lbase + mi * 16 + qr + i;
        int o = n0 + ni * 16 + (lane & 15);
        out[((size_t)(b * 256 + o)) * 4096 + ll] = acc[mi][ni][i];
      }
}

extern "C" void kernel_launch(void* const* d_in, const int* in_sizes, int n_in,
                              void* d_out, int out_size, void* d_ws, size_t ws_size,
                              hipStream_t stream) {
  const float* x     = (const float*)d_in[0];
  const float* Wq    = (const float*)d_in[1];
  const float* Wk    = (const float*)d_in[2];
  const float* Wv    = (const float*)d_in[3];
  const float* Wc    = (const float*)d_in[4];
  const float* Wout  = (const float*)d_in[5];
  const float* gamma = (const float*)d_in[6];
  const float* beta  = (const float*)d_in[7];
  float* out = (float*)d_out;
  char* ws = (char*)d_ws;
  unsigned short* Xt  = (unsigned short*)(ws);
  unsigned short* TV  = (unsigned short*)(ws + 134217728ull);
  unsigned short* Wtv = (unsigned short*)(ws + 402653184ull);
  unsigned short* W2  = (unsigned short*)(ws + 402915328ull);
  float* stats        = (float*)(ws + 403177472ull);

  k_prep<<<513, 256, 0, stream>>>(Wq, Wk, Wv, Wc, Wout, Wtv, W2, stats);
  k_transpose<<<16384, 256, 0, stream>>>(x, Xt);
  k_gemm_tv<<<4096, 256, 0, stream>>>(Xt, Wtv, TV);
  k_attn<<<4096, 256, 0, stream>>>(Xt, TV);
  k_stats<<<4096, 256, 0, stream>>>(TV, stats);
  k_finalize<<<1, 64, 0, stream>>>(stats);
  k_gemm_out<<<4096, 256, 0, stream>>>(Xt, TV, W2, stats, gamma, beta, out);
}

// Round 2
// 903.429 us; speedup vs baseline: 1.9961x; 1.9961x over previous
//
#include <hip/hip_runtime.h>

// B=64, C=256, L=4096. Tokens b-major: t = b*4096 + l.
// ws: Xt bf16[262144][256] @0 (128MB); Virt bf16[262144][256] @128MB (128MB);
//     Wtv bf16[512][256] @256MB; Wout2 bf16[256][512]; stats fp32[4224]
//     stats: [32][128] partial (sum,b | sumsq,b) then mean[64]@4096, rstd[64]@4160

typedef __attribute__((ext_vector_type(8))) short          v8s;   // 8 x bf16 bits
typedef __attribute__((ext_vector_type(8))) unsigned short v8u;
typedef __attribute__((ext_vector_type(4))) float          f32x4;

#define MFMA16(a, b, c) __builtin_amdgcn_mfma_f32_16x16x32_bf16((a), (b), (c), 0, 0, 0)

static __device__ __forceinline__ unsigned short f2bf(float f) {
  union { float f; unsigned u; } v; v.f = f;
  unsigned r = (v.u + 0x7FFFu + ((v.u >> 16) & 1u)) >> 16;  // RNE
  return (unsigned short)r;
}
static __device__ __forceinline__ float bf2f(unsigned short h) {
  union { unsigned u; float f; } v; v.u = ((unsigned)h) << 16; return v.f;
}

// ---------------- prep: M = Wq^T Wk / 16, W2 = Wout*Wc, bf16 packs, zero stats
__global__ void k_prep(const float* __restrict__ Wq, const float* __restrict__ Wk,
                       const float* __restrict__ Wv, const float* __restrict__ Wc,
                       const float* __restrict__ Wout,
                       unsigned short* __restrict__ Wtv,    // [512][256]
                       unsigned short* __restrict__ Wout2,  // [256][512]
                       float* __restrict__ stats) {
  int bid = blockIdx.x, j = threadIdx.x;
  if (bid < 256) {
    int i = bid;
    float acc = 0.f;
    for (int c = 0; c < 256; ++c) acc += Wq[c * 256 + i] * Wk[c * 256 + j];
    Wtv[i * 256 + j] = f2bf(acc * 0.0625f);               // M row i (1/sqrt(C) folded)
    Wtv[(256 + i) * 256 + j] = f2bf(Wv[i * 256 + j]);     // Wv row i
  } else if (bid < 512) {
    int o = bid - 256;
    float acc = 0.f;
    for (int c = 0; c < 256; ++c) acc += Wout[o * 256 + c] * Wc[c * 256 + j];
    Wout2[o * 512 + 256 + j] = f2bf(acc);                 // W2 = Wout*Wc
    Wout2[o * 512 + j] = f2bf(Wout[o * 256 + j]);         // Wout
  } else {
    stats[(bid - 512) * 256 + j] = 0.f;                   // zero 4096 partials
  }
}

// ---------------- x (B,C,L) fp32 -> Xt[t][c] bf16 (LDS-tiled 64x64 transpose)
__global__ void k_transpose(const float* __restrict__ x, unsigned short* __restrict__ Xt) {
  __shared__ float tile[64 * 65];
  int bid = blockIdx.x;
  int b = bid >> 8, cb = (bid >> 6) & 3, lb = bid & 63;
  int c0 = cb * 64, l0 = lb * 64, t = threadIdx.x;
#pragma unroll
  for (int i = 0; i < 4; ++i) {
    int idx = i * 256 + t, r = idx >> 4, ch = idx & 15;
    float4 v = *(const float4*)(x + ((size_t)(b * 256 + c0 + r)) * 4096 + l0 + ch * 4);
    tile[r * 65 + ch * 4 + 0] = v.x; tile[r * 65 + ch * 4 + 1] = v.y;
    tile[r * 65 + ch * 4 + 2] = v.z; tile[r * 65 + ch * 4 + 3] = v.w;
  }
  __syncthreads();
#pragma unroll
  for (int i = 0; i < 2; ++i) {
    int idx = i * 256 + t, r = idx >> 3, ch = idx & 7;
    v8u o;
#pragma unroll
    for (int j = 0; j < 8; ++j) o[j] = f2bf(tile[(ch * 8 + j) * 65 + r]);
    *(v8u*)(Xt + ((size_t)(b * 4096 + l0 + r)) * 256 + c0 + ch * 8) = o;
  }
}

// ---------------- fused per-l: T/V gemm -> S -> softmax -> P*V -> virt + GN stats
// LDS layout (byte offsets): Xs[64][264]@0, Ts[64][264]@33792, VTs[256][72]@67584,
//   Ps[64][72]@104448, Ss f32[64][65]@113664, red f32[64][4]@130304, rowv f32[64]@131328
__global__ __launch_bounds__(512) void k_fused(const unsigned short* __restrict__ Xt,
                                               const unsigned short* __restrict__ Wtv,
                                               unsigned short* __restrict__ Virt,
                                               float* __restrict__ stats) {
  extern __shared__ char smem[];
  unsigned short* Xs  = (unsigned short*)(smem);
  unsigned short* Ts  = (unsigned short*)(smem + 33792);
  unsigned short* VTs = (unsigned short*)(smem + 67584);
  unsigned short* Ps  = (unsigned short*)(smem + 104448);
  float*          Ss  = (float*)(smem + 113664);
  float*          red = (float*)(smem + 130304);
  float*          rowv= (float*)(smem + 131328);

  int l = blockIdx.x, t = threadIdx.x, lane = t & 63, wv = t >> 6;
  int fr = lane & 15, kq = (lane >> 4) * 8, qr = (lane >> 4) * 4;

  // stage X_l: 64 rows (b) x 256 ch
#pragma unroll
  for (int i = 0; i < 4; ++i) {
    int idx = i * 512 + t, r = idx >> 5, ch = idx & 31;
    *(v8u*)(Xs + r * 264 + ch * 8) = *(const v8u*)(Xt + ((size_t)(r * 4096 + l)) * 256 + ch * 8);
  }
  __syncthreads();

  {  // Phase 1: [T|V] = Xs * Wtv^T  (64 x 512, K=256), B-frags direct from global (L2-hot)
    int n0 = wv * 64;
    f32x4 acc[4][4];
#pragma unroll
    for (int mi = 0; mi < 4; ++mi)
#pragma unroll
      for (int ni = 0; ni < 4; ++ni) acc[mi][ni] = (f32x4){0.f, 0.f, 0.f, 0.f};
#pragma unroll
    for (int kc = 0; kc < 8; ++kc) {
      v8s a[4], b[4];
#pragma unroll
      for (int mi = 0; mi < 4; ++mi) a[mi] = *(const v8s*)(Xs + (mi * 16 + fr) * 264 + kc * 32 + kq);
#pragma unroll
      for (int ni = 0; ni < 4; ++ni)
        b[ni] = *(const v8s*)(Wtv + (n0 + ni * 16 + fr) * 256 + kc * 32 + kq);
#pragma unroll
      for (int mi = 0; mi < 4; ++mi)
#pragma unroll
        for (int ni = 0; ni < 4; ++ni) acc[mi][ni] = MFMA16(a[mi], b[ni], acc[mi][ni]);
    }
    if (wv < 4) {  // T rows (d-token, channel) row-major
#pragma unroll
      for (int mi = 0; mi < 4; ++mi)
#pragma unroll
        for (int ni = 0; ni < 4; ++ni)
#pragma unroll
          for (int i = 0; i < 4; ++i)
            Ts[(mi * 16 + qr + i) * 264 + n0 + ni * 16 + fr] = f2bf(acc[mi][ni][i]);
    } else {       // V transposed: VTs[c][d]
#pragma unroll
      for (int mi = 0; mi < 4; ++mi)
#pragma unroll
        for (int ni = 0; ni < 4; ++ni)
#pragma unroll
          for (int i = 0; i < 4; ++i)
            VTs[(n0 - 256 + ni * 16 + fr) * 72 + mi * 16 + qr + i] = f2bf(acc[mi][ni][i]);
    }
  }
  __syncthreads();

  {  // Phase 2: S = Xs * Ts^T  (64 x 64, K=256); 16 tiles, 2 per wave
    f32x4 acc[2];
    acc[0] = (f32x4){0.f, 0.f, 0.f, 0.f};
    acc[1] = (f32x4){0.f, 0.f, 0.f, 0.f};
    int tid0 = wv * 2;
#pragma unroll
    for (int kc = 0; kc < 8; ++kc) {
#pragma unroll
      for (int j = 0; j < 2; ++j) {
        int mi = (tid0 + j) >> 2, ni = (tid0 + j) & 3;
        v8s a = *(const v8s*)(Xs + (mi * 16 + fr) * 264 + kc * 32 + kq);
        v8s b = *(const v8s*)(Ts + (ni * 16 + fr) * 264 + kc * 32 + kq);
        acc[j] = MFMA16(a, b, acc[j]);
      }
    }
#pragma unroll
    for (int j = 0; j < 2; ++j) {
      int mi = (tid0 + j) >> 2, ni = (tid0 + j) & 3;
#pragma unroll
      for (int i = 0; i < 4; ++i)
        Ss[(mi * 16 + qr + i) * 65 + ni * 16 + fr] = acc[j][i];
    }
  }
  __syncthreads();

  // Phase 3: softmax over d (row direction), P = exp(S-m) in bf16; 1/sum into rowv
  if (t < 256) {
    int r = t >> 2, seg = t & 3;
    float pm = -1e30f;
    for (int j = seg * 16; j < seg * 16 + 16; ++j) pm = fmaxf(pm, Ss[r * 65 + j]);
    red[r * 4 + seg] = pm;
  }
  __syncthreads();
  if (t < 64) rowv[t] = fmaxf(fmaxf(red[t * 4], red[t * 4 + 1]), fmaxf(red[t * 4 + 2], red[t * 4 + 3]));
  __syncthreads();
  if (t < 256) {
    int r = t >> 2, seg = t & 3;
    float m = rowv[r], ps = 0.f;
    for (int j = seg * 16; j < seg * 16 + 16; ++j) {
      float e = __expf(Ss[r * 65 + j] - m);
      Ps[r * 72 + j] = f2bf(e);
      ps += e;
    }
    red[r * 4 + seg] = ps;
  }
  __syncthreads();
  if (t < 64) rowv[t] = 1.f / (red[t * 4] + red[t * 4 + 1] + red[t * 4 + 2] + red[t * 4 + 3]);
  __syncthreads();

  {  // Phase 4: virt = diag(rowv) * P * V  (64 x 256, K=64) -> repack into Ts
    int n0 = wv * 32;
    f32x4 acc[4][2];
#pragma unroll
    for (int mi = 0; mi < 4; ++mi) { acc[mi][0] = (f32x4){0,0,0,0}; acc[mi][1] = (f32x4){0,0,0,0}; }
#pragma unroll
    for (int kc = 0; kc < 2; ++kc) {
      v8s a[4], b[2];
#pragma unroll
      for (int mi = 0; mi < 4; ++mi) a[mi] = *(const v8s*)(Ps + (mi * 16 + fr) * 72 + kc * 32 + kq);
#pragma unroll
      for (int ni = 0; ni < 2; ++ni)
        b[ni] = *(const v8s*)(VTs + (n0 + ni * 16 + fr) * 72 + kc * 32 + kq);
#pragma unroll
      for (int mi = 0; mi < 4; ++mi)
#pragma unroll
        for (int ni = 0; ni < 2; ++ni) acc[mi][ni] = MFMA16(a[mi], b[ni], acc[mi][ni]);
    }
    __syncthreads();  // Ts (T) dead; reuse for virt repack
#pragma unroll
    for (int mi = 0; mi < 4; ++mi)
#pragma unroll
      for (int i = 0; i < 4; ++i) {
        float inv = rowv[mi * 16 + qr + i];
#pragma unroll
        for (int ni = 0; ni < 2; ++ni)
          Ts[(mi * 16 + qr + i) * 264 + n0 + ni * 16 + fr] = f2bf(acc[mi][ni][i] * inv);
      }
  }
  __syncthreads();

  {  // Phase 5: coalesced virt store + fused GN partial stats
    int r = t >> 3, seg = t & 7;  // 8 threads per row, 32 channels each
    float s = 0.f, s2 = 0.f;
#pragma unroll
    for (int c4 = 0; c4 < 4; ++c4) {
      v8u v = *(const v8u*)(Ts + r * 264 + seg * 32 + c4 * 8);
#pragma unroll
      for (int j = 0; j < 8; ++j) { float f = bf2f(v[j]); s += f; s2 += f * f; }
      *(v8u*)(Virt + ((size_t)(r * 4096 + l)) * 256 + seg * 32 + c4 * 8) = v;
    }
#pragma unroll
    for (int o = 4; o > 0; o >>= 1) { s += __shfl_xor(s, o); s2 += __shfl_xor(s2, o); }
    if (seg == 0) {
      int slot = blockIdx.x & 31;
      atomicAdd(&stats[slot * 128 + r], s);
      atomicAdd(&stats[slot * 128 + 64 + r], s2);
    }
  }
}

__global__ void k_finalize(float* __restrict__ stats) {
  int t = threadIdx.x;
  if (t < 64) {
    float s = 0.f, s2 = 0.f;
    for (int sl = 0; sl < 32; ++sl) { s += stats[sl * 128 + t]; s2 += stats[sl * 128 + 64 + t]; }
    const float inv = 1.f / 1048576.f;  // C*L
    float m = s * inv;
    float var = s2 * inv - m * m;
    stats[4096 + t] = m;
    stats[4160 + t] = rsqrtf(var + 1e-5f);
  }
}

// ---------------- out = [Xt | relu(gn(virt))] * [Wout | W2]^T : K=512, BM=64, BN=256
__global__ void k_gemm_out(const unsigned short* __restrict__ Xt,
                           const unsigned short* __restrict__ Virt,
                           const unsigned short* __restrict__ Wout2,
                           const float* __restrict__ stats,
                           const float* __restrict__ gamma,
                           const float* __restrict__ beta,
                           float* __restrict__ out) {
  __shared__ unsigned short As[64 * 72];
  __shared__ unsigned short Bs[256 * 72];
  int t = threadIdx.x, lane = t & 63, wv = t >> 6;
  size_t t0 = (size_t)blockIdx.x * 64;
  int b = (int)(t0 >> 12);
  float mean = stats[4096 + b], rstd = stats[4160 + b];  // uniform per block (64 | 4096)
  int n0 = wv * 64;
  f32x4 acc[4][4];
#pragma unroll
  for (int mi = 0; mi < 4; ++mi)
#pragma unroll
    for (int ni = 0; ni < 4; ++ni) acc[mi][ni] = (f32x4){0.f, 0.f, 0.f, 0.f};
  for (int kc = 0; kc < 8; ++kc) {
    __syncthreads();
#pragma unroll
    for (int i = 0; i < 2; ++i) {  // stage A (64 x 64)
      int idx = i * 256 + t, r = idx >> 3, ch = idx & 7;
      if (kc < 4) {
        *(v8u*)(As + r * 72 + ch * 8) = *(const v8u*)(Xt + (t0 + r) * 256 + kc * 64 + ch * 8);
      } else {
        v8u v = *(const v8u*)(Virt + (t0 + r) * 256 + (kc - 4) * 64 + ch * 8);
        int cb = (kc - 4) * 64 + ch * 8;
        float4 g0 = *(const float4*)(gamma + cb), g1 = *(const float4*)(gamma + cb + 4);
        float4 bb0 = *(const float4*)(beta + cb), bb1 = *(const float4*)(beta + cb + 4);
        float gs[8] = {g0.x, g0.y, g0.z, g0.w, g1.x, g1.y, g1.z, g1.w};
        float bs[8] = {bb0.x, bb0.y, bb0.z, bb0.w, bb1.x, bb1.y, bb1.z, bb1.w};
        v8u o;
#pragma unroll
        for (int j = 0; j < 8; ++j) {
          float z = (bf2f(v[j]) - mean) * rstd * gs[j] + bs[j];
          o[j] = f2bf(fmaxf(z, 0.f));
        }
        *(v8u*)(As + r * 72 + ch * 8) = o;
      }
    }
#pragma unroll
    for (int i = 0; i < 8; ++i) {  // stage B (256 x 64)
      int idx = i * 256 + t, r = idx >> 3, ch = idx & 7;
      *(v8u*)(Bs + r * 72 + ch * 8) = *(const v8u*)(Wout2 + r * 512 + kc * 64 + ch * 8);
    }
    __syncthreads();
#pragma unroll
    for (int ks = 0; ks < 2; ++ks) {
      int kq = ks * 32 + (lane >> 4) * 8;
      v8s a[4], bb[4];
#pragma unroll
      for (int mi = 0; mi < 4; ++mi) a[mi] = *(const v8s*)(As + (mi * 16 + (lane & 15)) * 72 + kq);
#pragma unroll
      for (int ni = 0; ni < 4; ++ni)
        bb[ni] = *(const v8s*)(Bs + (n0 + ni * 16 + (lane & 15)) * 72 + kq);
#pragma unroll
      for (int mi = 0; mi < 4; ++mi)
#pragma unroll
        for (int ni = 0; ni < 4; ++ni) acc[mi][ni] = MFMA16(a[mi], bb[ni], acc[mi][ni]);
    }
  }
  int qr = (lane >> 4) * 4, lbase = (int)(t0 & 4095);
#pragma unroll
  for (int mi = 0; mi < 4; ++mi)
#pragma unroll
    for (int ni = 0; ni < 4; ++ni)
#pragma unroll
      for (int i = 0; i < 4; ++i) {
        int ll = lbase + mi * 16 + qr + i;
        int o = n0 + ni * 16 + (lane & 15);
        out[((size_t)(b * 256 + o)) * 4096 + ll] = acc[mi][ni][i];
      }
}

extern "C" void kernel_launch(void* const* d_in, const int* in_sizes, int n_in,
                              void* d_out, int out_size, void* d_ws, size_t ws_size,
                              hipStream_t stream) {
  const float* x     = (const float*)d_in[0];
  const float* Wq    = (const float*)d_in[1];
  const float* Wk    = (const float*)d_in[2];
  const float* Wv    = (const float*)d_in[3];
  const float* Wc    = (const float*)d_in[4];
  const float* Wout  = (const float*)d_in[5];
  const float* gamma = (const float*)d_in[6];
  const float* beta  = (const float*)d_in[7];
  float* out = (float*)d_out;
  char* ws = (char*)d_ws;
  unsigned short* Xt   = (unsigned short*)(ws);
  unsigned short* Virt = (unsigned short*)(ws + 134217728ull);
  unsigned short* Wtv  = (unsigned short*)(ws + 268435456ull);
  unsigned short* W2   = (unsigned short*)(ws + 268697600ull);
  float* stats         = (float*)(ws + 268959744ull);

  static const int kFusedLds = 131584;
  hipFuncSetAttribute((const void*)k_fused, hipFuncAttributeMaxDynamicSharedMemorySize,
                      kFusedLds);  // idempotent host-side call; capture-safe

  k_prep<<<528, 256, 0, stream>>>(Wq, Wk, Wv, Wc, Wout, Wtv, W2, stats);
  k_transpose<<<16384, 256, 0, stream>>>(x, Xt);
  k_fused<<<4096, 512, kFusedLds, stream>>>(Xt, Wtv, Virt, stats);
  k_finalize<<<1, 64, 0, stream>>>(stats);
  k_gemm_out<<<4096, 256, 0, stream>>>(Xt, Virt, W2, stats, gamma, beta, out);
}